// Round 1
// 255.556 us; speedup vs baseline: 1.0532x; 1.0532x over previous
//
#include <hip/hip_runtime.h>
#include <math.h>

// Round 6: mega-fusion. q-proj GEMM + 8-head attention + out-proj GEMM run in
// ONE kernel per (b, 128-row T-tile); q and att live in LDS only (no qo HBM
// round trip: saves ~168 MB of traffic + 2 launch gaps). K/V are pre-padded,
// pre-transposed to bf16 once by prep_kv_kernel so attention staging is two
// linear global_load_lds rounds (no per-block f2bf, no scattered LDS writes).

#define NUM_HEADS 8
#define DIM_HEAD 40
#define INNER 320
#define DQ 320
#define DC 768
#define SEQ_T 4096
#define SEQ_S 77
#define BATCH 16
#define M_TOTAL (BATCH * SEQ_T)  // 65536
#define MKV 1232                  // BATCH*SEQ_S
#define MKV_PAD 1280
#define SCALE 0.39763536438352531f

typedef __attribute__((ext_vector_type(8))) short short8;
typedef __attribute__((ext_vector_type(4))) float floatx4;

__device__ __forceinline__ unsigned short f2bf(float f) {
  unsigned u = __float_as_uint(f);
  u += 0x7FFFu + ((u >> 16) & 1u);   // RNE
  return (unsigned short)(u >> 16);
}

// ------------------------------------------------------- convert ctx to bf16
#define CTXBLKS (MKV_PAD * DC / 8 / 256)        // 480
__global__ __launch_bounds__(256) void convert_ctx_kernel(
    const float* __restrict__ ctx, unsigned short* __restrict__ ctxb) {
  size_t t = (size_t)blockIdx.x * 256 + threadIdx.x;  // 8-short unit
  int row = (int)(t / (DC / 8)), col = (int)(t % (DC / 8)) * 8;
  int4 pk = make_int4(0, 0, 0, 0);
  if (row < MKV) {
    const float* p = &ctx[(size_t)row * DC + col];
    float4 a = *(const float4*)p, b = *(const float4*)(p + 4);
    pk.x = (int)(f2bf(a.x) | ((unsigned)f2bf(a.y) << 16));
    pk.y = (int)(f2bf(a.z) | ((unsigned)f2bf(a.w) << 16));
    pk.z = (int)(f2bf(b.x) | ((unsigned)f2bf(b.y) << 16));
    pk.w = (int)(f2bf(b.z) | ((unsigned)f2bf(b.w) << 16));
  }
  *(int4*)&ctxb[(size_t)row * DC + col] = pk;
}

// -------------------------------------- transpose weights (fp32 -> bf16^T)
__global__ __launch_bounds__(256) void transpose_w_kernel(
    const float* __restrict__ Wq, const float* __restrict__ Wo,
    const float* __restrict__ Wk, const float* __restrict__ Wv,
    unsigned short* __restrict__ WqT, unsigned short* __restrict__ WoT,
    unsigned short* __restrict__ WkvT) {
  const int z = blockIdx.z;
  const float* W; unsigned short* WT; int KD; float scl = 1.0f;
  if (z == 0)      { W = Wq; WT = WqT;  KD = 320; }
  else if (z == 1) { W = Wo; WT = WoT;  KD = 320; }
  else if (z == 2) { W = Wk; WT = WkvT; KD = DC; scl = SCALE; }
  else             { W = Wv; WT = WkvT + (size_t)INNER * DC; KD = DC; }
  const int k0 = blockIdx.x * 32;
  if (k0 >= KD) return;
  const int n0 = blockIdx.y * 32;
  __shared__ float tile[32][33];
  int tx = threadIdx.x & 31, ty = threadIdx.x >> 5;
  #pragma unroll
  for (int r = 0; r < 4; ++r)
    tile[ty + r * 8][tx] = W[(size_t)(k0 + ty + r * 8) * 320 + n0 + tx];
  __syncthreads();
  #pragma unroll
  for (int r = 0; r < 4; ++r)
    WT[(size_t)(n0 + ty + r * 8) * KD + k0 + tx] = f2bf(tile[tx][ty + r * 8] * scl);
}

// ------------------------------------------- bf16 MFMA GEMM, 128x160 (kv path)
#define GBM 128
#define GBN 160
#define GBK 64

template <bool OUT_BF16, int K, int CN>
__global__ __launch_bounds__(256) void gemm_mfma_kernel(
    const unsigned short* __restrict__ A, const unsigned short* __restrict__ B,
    void* __restrict__ C, const float* __restrict__ bias, float scale) {
  __shared__ __align__(16) unsigned short As[GBM * GBK];
  __shared__ __align__(16) unsigned short Bs[GBN * GBK];
  const int tid = threadIdx.x;
  const int lane = tid & 63, wave = tid >> 6;
  const int wm = (wave & 1) * 64, wn = (wave >> 1) * 80;
  const int lrow = lane & 15, quad = lane >> 4;
  const unsigned short* Ab = A + (size_t)blockIdx.x * GBM * K;
  const unsigned short* Bb = B + (size_t)blockIdx.y * GBN * K;

  floatx4 acc[4][5];
  #pragma unroll
  for (int i = 0; i < 4; ++i)
    #pragma unroll
    for (int j = 0; j < 5; ++j) acc[i][j] = (floatx4){0.f, 0.f, 0.f, 0.f};

  for (int kb = 0; kb < K / GBK; ++kb) {
    const int k0 = kb * GBK;
    #pragma unroll
    for (int rnd = 0; rnd < 4; ++rnd) {
      int off = rnd * 4096 + tid * 16;
      int m = off >> 7, cl = (off >> 4) & 7, cg = cl ^ (m & 7);
      __builtin_amdgcn_global_load_lds(
          (const __attribute__((address_space(1))) void*)(Ab + (size_t)m * K + k0 + cg * 8),
          (__attribute__((address_space(3))) void*)((char*)As + off), 16, 0, 0);
    }
    #pragma unroll
    for (int rnd = 0; rnd < 5; ++rnd) {
      int off = rnd * 4096 + tid * 16;
      int n = off >> 7, cl = (off >> 4) & 7, cg = cl ^ (n & 7);
      __builtin_amdgcn_global_load_lds(
          (const __attribute__((address_space(1))) void*)(Bb + (size_t)n * K + k0 + cg * 8),
          (__attribute__((address_space(3))) void*)((char*)Bs + off), 16, 0, 0);
    }
    __syncthreads();
    #pragma unroll
    for (int ks = 0; ks < 2; ++ks) {
      short8 fa[4], fb[5];
      #pragma unroll
      for (int i = 0; i < 4; ++i) {
        int m = wm + i * 16 + lrow;
        int cl = (ks * 4 + quad) ^ (m & 7);
        fa[i] = *(const short8*)&As[m * GBK + cl * 8];
      }
      #pragma unroll
      for (int j = 0; j < 5; ++j) {
        int n = wn + j * 16 + lrow;
        int cl = (ks * 4 + quad) ^ (n & 7);
        fb[j] = *(const short8*)&Bs[n * GBK + cl * 8];
      }
      #pragma unroll
      for (int i = 0; i < 4; ++i)
        #pragma unroll
        for (int j = 0; j < 5; ++j)
          acc[i][j] = __builtin_amdgcn_mfma_f32_16x16x32_bf16(fa[i], fb[j], acc[i][j], 0, 0, 0);
    }
    __syncthreads();
  }
  #pragma unroll
  for (int i = 0; i < 4; ++i)
    #pragma unroll
    for (int j = 0; j < 5; ++j) {
      int n = blockIdx.y * GBN + wn + j * 16 + lrow;
      float bv = bias ? bias[n] : 0.f;
      #pragma unroll
      for (int r = 0; r < 4; ++r) {
        size_t m = (size_t)blockIdx.x * GBM + wm + i * 16 + quad * 4 + r;
        float val = acc[i][j][r] * scale + bv;
        if (OUT_BF16) ((unsigned short*)C)[m * CN + n] = f2bf(val);
        else          ((float*)C)[m * CN + n] = val;
      }
    }
}

// ---------------- prep_kv: kvw fp32 [1280][640] -> per-(b,h) packed bf16 tile
// kvp[(b*8+h)] = K [80][40] (rows>=77 zero) | Vt [48][104] (pad zero)
// 8192 shorts = 16384 B per (b,h): exactly 2 linear global_load_lds rounds
// for a 512-thread block in the fused kernel.
__global__ __launch_bounds__(256) void prep_kv_kernel(
    const float* __restrict__ kvw, unsigned short* __restrict__ kvp) {
  const int b = blockIdx.x >> 3, h = blockIdx.x & 7;
  unsigned short* dst = kvp + (size_t)blockIdx.x * 8192;
  const float* kvb = kvw + (size_t)b * SEQ_S * 640;
  for (int i = threadIdx.x; i < 3200; i += 256) {       // K [80][40]
    int s = i / 40, c = i % 40;
    unsigned short v = 0;
    if (s < SEQ_S) v = f2bf(kvb[(size_t)s * 640 + h * DIM_HEAD + c]);
    dst[i] = v;
  }
  for (int i = threadIdx.x; i < 4992; i += 256) {       // Vt [48][104]
    int c = i / 104, s = i % 104;
    unsigned short v = 0;
    if (s < SEQ_S && c < DIM_HEAD)
      v = f2bf(kvb[(size_t)s * 640 + 320 + h * DIM_HEAD + c]);
    dst[3200 + i] = v;
  }
}

// --------------------------------------------------------------- fused kernel
// grid = (B * T/128) = 512 blocks, 512 threads (8 waves x 16 q-rows in attn,
// 2x4 wave grid in the GEMM phases). LDS 141,312 B -> 1 block/CU.
// Layout (shorts): qs [128][328] @ 0 (q, then att in-place per head band);
// stage @ 41984 (28672): phase1 As[128*64]|Bs[320*64]; phase2 overlay
// Kb[80*40] | Vt[48*104] | Pw 8x[16*104]; phase3 Bs only.
#define QS_STRIDE 328
#define LDS_STAGE 41984

__global__ __launch_bounds__(512) void fused_attn_kernel(
    const float* __restrict__ x, const unsigned short* __restrict__ WqT,
    const unsigned short* __restrict__ kvp, const unsigned short* __restrict__ WoT,
    const float* __restrict__ bo, float* __restrict__ out) {
  __shared__ __align__(16) unsigned short lds[70656];   // 141,312 B
  unsigned short* qs = lds;
  unsigned short* As = lds + LDS_STAGE;
  unsigned short* Bs = lds + LDS_STAGE + 8192;
  const int tid = threadIdx.x;
  const int lane = tid & 63, wave = tid >> 6;
  const int lrow = lane & 15, quad = lane >> 4;
  const int b = blockIdx.x >> 5;
  const int t0 = (blockIdx.x & 31) * 128;
  const int wm = (wave & 1) * 64, wn = (wave >> 1) * 80;

  // ---- Phase 1: qs = bf16(SCALE * x[t0:t0+128] @ Wq) ----
  {
    const float* xb = x + ((size_t)b * SEQ_T + t0) * DQ;
    floatx4 acc[4][5];
    #pragma unroll
    for (int i = 0; i < 4; ++i)
      #pragma unroll
      for (int j = 0; j < 5; ++j) acc[i][j] = (floatx4){0.f, 0.f, 0.f, 0.f};
    for (int kb = 0; kb < 5; ++kb) {
      const int k0 = kb * 64;
      #pragma unroll
      for (int rnd = 0; rnd < 2; ++rnd) {     // As: fp32 -> bf16 convert-stage
        int off = rnd * 8192 + tid * 16;
        int m = off >> 7, cl = (off >> 4) & 7, cg = cl ^ (m & 7);
        const float* src = xb + (size_t)m * DQ + k0 + cg * 8;
        float4 a = *(const float4*)src, c = *(const float4*)(src + 4);
        short8 pk;
        pk[0] = (short)f2bf(a.x); pk[1] = (short)f2bf(a.y);
        pk[2] = (short)f2bf(a.z); pk[3] = (short)f2bf(a.w);
        pk[4] = (short)f2bf(c.x); pk[5] = (short)f2bf(c.y);
        pk[6] = (short)f2bf(c.z); pk[7] = (short)f2bf(c.w);
        *(short8*)((char*)As + off) = pk;
      }
      #pragma unroll
      for (int rnd = 0; rnd < 5; ++rnd) {     // Bs: WqT chunk
        int off = rnd * 8192 + tid * 16;
        int n = off >> 7, cl = (off >> 4) & 7, cg = cl ^ (n & 7);
        __builtin_amdgcn_global_load_lds(
            (const __attribute__((address_space(1))) void*)(WqT + (size_t)n * 320 + k0 + cg * 8),
            (__attribute__((address_space(3))) void*)((char*)Bs + off), 16, 0, 0);
      }
      __syncthreads();
      #pragma unroll
      for (int ks = 0; ks < 2; ++ks) {
        short8 fa[4], fb[5];
        #pragma unroll
        for (int i = 0; i < 4; ++i) {
          int m = wm + i * 16 + lrow;
          int cl = (ks * 4 + quad) ^ (m & 7);
          fa[i] = *(const short8*)&As[m * 64 + cl * 8];
        }
        #pragma unroll
        for (int j = 0; j < 5; ++j) {
          int n = wn + j * 16 + lrow;
          int cl = (ks * 4 + quad) ^ (n & 7);
          fb[j] = *(const short8*)&Bs[n * 64 + cl * 8];
        }
        #pragma unroll
        for (int i = 0; i < 4; ++i)
          #pragma unroll
          for (int j = 0; j < 5; ++j)
            acc[i][j] = __builtin_amdgcn_mfma_f32_16x16x32_bf16(fa[i], fb[j], acc[i][j], 0, 0, 0);
      }
      __syncthreads();
    }
    #pragma unroll
    for (int i = 0; i < 4; ++i)
      #pragma unroll
      for (int j = 0; j < 5; ++j)
        #pragma unroll
        for (int r = 0; r < 4; ++r)
          qs[(wm + i * 16 + quad * 4 + r) * QS_STRIDE + wn + j * 16 + lrow] =
              f2bf(acc[i][j][r] * SCALE);
  }
  __syncthreads();   // qs visible to all waves (phase-2 row mapping differs)

  // ---- Phase 2: attention, head loop; att overwrites qs band [h*40,h*40+40)
  {
    unsigned short* Kb = lds + LDS_STAGE;                        // [80][40]
    unsigned short* Vt = lds + LDS_STAGE + 3200;                 // [48][104]
    unsigned short* Pw = lds + LDS_STAGE + 8192 + wave * 1664;   // [16][104]
    const short8 zero8 = {0, 0, 0, 0, 0, 0, 0, 0};
    for (int h = 0; h < NUM_HEADS; ++h) {
      const unsigned short* kvbh = kvp + (size_t)(b * NUM_HEADS + h) * 8192;
      #pragma unroll
      for (int rnd = 0; rnd < 2; ++rnd) {   // linear 16 KB: K then Vt
        int off = rnd * 8192 + tid * 16;
        __builtin_amdgcn_global_load_lds(
            (const __attribute__((address_space(1))) void*)((const char*)kvbh + off),
            (__attribute__((address_space(3))) void*)((char*)Kb + off), 16, 0, 0);
      }
      __syncthreads();
      const int qrow = wave * 16 + lrow;
      short8 fq0 = *(const short8*)&qs[qrow * QS_STRIDE + h * DIM_HEAD + quad * 8];
      short8 fq1 = (quad == 0)
                       ? *(const short8*)&qs[qrow * QS_STRIDE + h * DIM_HEAD + 32]
                       : zero8;
      floatx4 sc[5];
      #pragma unroll
      for (int j = 0; j < 5; ++j) sc[j] = (floatx4){0.f, 0.f, 0.f, 0.f};
      #pragma unroll
      for (int j = 0; j < 5; ++j) {
        int srow = j * 16 + lrow;
        short8 fb0 = *(const short8*)&Kb[srow * 40 + quad * 8];
        short8 fb1 = *(const short8*)&Kb[srow * 40 + 32 + quad * 8];  // x0 for quad!=0
        sc[j] = __builtin_amdgcn_mfma_f32_16x16x32_bf16(fq0, fb0, sc[j], 0, 0, 0);
        sc[j] = __builtin_amdgcn_mfma_f32_16x16x32_bf16(fq1, fb1, sc[j], 0, 0, 0);
      }
      float lsum[4] = {0.f, 0.f, 0.f, 0.f};
      #pragma unroll
      for (int j = 0; j < 5; ++j) {
        int s = j * 16 + lrow;
        #pragma unroll
        for (int r = 0; r < 4; ++r) {
          float p = (s < SEQ_S) ? __expf(sc[j][r]) : 0.f;
          Pw[(quad * 4 + r) * 104 + s] = f2bf(p);
          lsum[r] += p;
        }
      }
      #pragma unroll
      for (int r = 0; r < 4; ++r) Pw[(quad * 4 + r) * 104 + 80 + lrow] = 0;
      #pragma unroll
      for (int r = 0; r < 4; ++r) {
        float v = lsum[r];
        v += __shfl_xor(v, 1); v += __shfl_xor(v, 2);
        v += __shfl_xor(v, 4); v += __shfl_xor(v, 8);
        lsum[r] = 1.0f / v;
      }
      floatx4 oc[3];
      #pragma unroll
      for (int nj = 0; nj < 3; ++nj) oc[nj] = (floatx4){0.f, 0.f, 0.f, 0.f};
      #pragma unroll
      for (int ks = 0; ks < 3; ++ks) {   // Pw wave-local: lgkmcnt ordering ok
        short8 pa = *(const short8*)&Pw[lrow * 104 + ks * 32 + quad * 8];
        #pragma unroll
        for (int nj = 0; nj < 3; ++nj) {
          short8 vb = *(const short8*)&Vt[(nj * 16 + lrow) * 104 + ks * 32 + quad * 8];
          oc[nj] = __builtin_amdgcn_mfma_f32_16x16x32_bf16(pa, vb, oc[nj], 0, 0, 0);
        }
      }
      #pragma unroll
      for (int nj = 0; nj < 3; ++nj) {   // att -> qs (wave-local rows)
        int c = nj * 16 + lrow;
        if (c < DIM_HEAD) {
          #pragma unroll
          for (int r = 0; r < 4; ++r)
            qs[(wave * 16 + quad * 4 + r) * QS_STRIDE + h * DIM_HEAD + c] =
                f2bf(oc[nj][r] * lsum[r]);
        }
      }
      __syncthreads();   // all Kb/Vt reads done before next head's restage
    }
  }

  // ---- Phase 3: out = att @ Wo + bo (A straight from qs LDS) ----
  {
    floatx4 acc[4][5];
    #pragma unroll
    for (int i = 0; i < 4; ++i)
      #pragma unroll
      for (int j = 0; j < 5; ++j) acc[i][j] = (floatx4){0.f, 0.f, 0.f, 0.f};
    for (int kb = 0; kb < 5; ++kb) {
      const int k0 = kb * 64;
      #pragma unroll
      for (int rnd = 0; rnd < 5; ++rnd) {
        int off = rnd * 8192 + tid * 16;
        int n = off >> 7, cl = (off >> 4) & 7, cg = cl ^ (n & 7);
        __builtin_amdgcn_global_load_lds(
            (const __attribute__((address_space(1))) void*)(WoT + (size_t)n * 320 + k0 + cg * 8),
            (__attribute__((address_space(3))) void*)((char*)Bs + off), 16, 0, 0);
      }
      __syncthreads();
      #pragma unroll
      for (int ks = 0; ks < 2; ++ks) {
        short8 fa[4], fb[5];
        #pragma unroll
        for (int i = 0; i < 4; ++i)
          fa[i] = *(const short8*)&qs[(wm + i * 16 + lrow) * QS_STRIDE + k0 + ks * 32 + quad * 8];
        #pragma unroll
        for (int j = 0; j < 5; ++j) {
          int n = wn + j * 16 + lrow;
          int cl = (ks * 4 + quad) ^ (n & 7);
          fb[j] = *(const short8*)&Bs[n * 64 + cl * 8];
        }
        #pragma unroll
        for (int i = 0; i < 4; ++i)
          #pragma unroll
          for (int j = 0; j < 5; ++j)
            acc[i][j] = __builtin_amdgcn_mfma_f32_16x16x32_bf16(fa[i], fb[j], acc[i][j], 0, 0, 0);
      }
      __syncthreads();
    }
    float* ob = out + ((size_t)b * SEQ_T + t0) * DQ;
    #pragma unroll
    for (int i = 0; i < 4; ++i)
      #pragma unroll
      for (int j = 0; j < 5; ++j) {
        int n = wn + j * 16 + lrow;
        float bv = bo[n];
        #pragma unroll
        for (int r = 0; r < 4; ++r)
          ob[(size_t)(wm + i * 16 + quad * 4 + r) * DQ + n] = acc[i][j][r] + bv;
      }
  }
}

// -------------------------------------------------------------------- launch
extern "C" void kernel_launch(void* const* d_in, const int* in_sizes, int n_in,
                              void* d_out, int out_size, void* d_ws, size_t ws_size,
                              hipStream_t stream) {
  const float* x   = (const float*)d_in[0];
  const float* ctx = (const float*)d_in[1];
  const float* Wq  = (const float*)d_in[2];
  const float* Wk  = (const float*)d_in[3];
  const float* Wv  = (const float*)d_in[4];
  const float* Wo  = (const float*)d_in[5];
  const float* bo  = (const float*)d_in[6];
  float* out = (float*)d_out;

  char* w = (char*)d_ws;
  unsigned short* ctxb = (unsigned short*)(w);             //  1,966,080 B
  unsigned short* WkvT = (unsigned short*)(w + 1966080);   //    983,040 B
  float*          kvw  = (float*)(w + 2949120);            //  3,276,800 B
  unsigned short* WqT  = (unsigned short*)(w + 6225920);   //    204,800 B
  unsigned short* WoT  = (unsigned short*)(w + 6430720);   //    204,800 B
  unsigned short* kvp  = (unsigned short*)(w + 6635520);   //  2,097,152 B -> 8,732,672

  hipLaunchKernelGGL(convert_ctx_kernel, dim3(CTXBLKS), dim3(256), 0, stream, ctx, ctxb);
  hipLaunchKernelGGL(transpose_w_kernel, dim3(24, 10, 4), dim3(256), 0, stream,
                     Wq, Wo, Wk, Wv, WqT, WoT, WkvT);
  hipLaunchKernelGGL((gemm_mfma_kernel<false, DC, 640>), dim3(MKV_PAD / GBM, 640 / GBN),
                     dim3(256), 0, stream, ctxb, WkvT, (void*)kvw, (const float*)nullptr, 1.0f);
  hipLaunchKernelGGL(prep_kv_kernel, dim3(BATCH * NUM_HEADS), dim3(256), 0, stream, kvw, kvp);
  hipLaunchKernelGGL(fused_attn_kernel, dim3(BATCH * (SEQ_T / 128)), dim3(512), 0, stream,
                     x, WqT, kvp, WoT, bo, out);
}